// Round 11
// baseline (229.267 us; speedup 1.0000x reference)
//
#include <hip/hip_runtime.h>
#include <hip/hip_bf16.h>
#include <math.h>

// B=2, N=2048, M=1024, H=16, DK=64. fp32 in/out.
// R25 = R23 qkv restored (256-thr; R24's 512-thr halved MFMA-per-barrier
// per wave 32->16 and cost +4us — lesson: keep >=32 MFMA/barrier/wave)
// + attn re-grid QBLK=64: 256 thr / 4 waves / 1024 blocks = 4 blocks/CU
// (LDS 40KB = K16 dbuf + V16 dbuf + Psh 4x2K). Same 16 waves/CU as the
// 128-row version but 4 independent 4-wave barrier domains instead of
// 2x8 -> finer interleave across the phase-locked pipeline. Per-wave
// inner code identical (w 0..3, 2 gll16 per array per wave). Risk: K/V
// L2 re-fetch doubles (FETCH ~86->~110MB) — HBM at 16% has headroom.
// Precision plan: all planes f16, 1-term everywhere; 1/8 scale AND log2e
// folded into Wq/bq; exp = raw v_exp_f32 (exp2). absmax 9.77e-4 stable.

typedef __attribute__((ext_vector_type(8))) _Float16 f16x8;
typedef __attribute__((ext_vector_type(4))) float f32x4;

typedef __attribute__((address_space(1))) void gvoid;   // global
typedef __attribute__((address_space(3))) void lvoid;   // LDS

// async 16B/lane global->LDS copy: 64 lanes -> 1KB at wave-uniform lds base
__device__ __forceinline__ void gll16(const void* g, void* l) {
    __builtin_amdgcn_global_load_lds(
        (gvoid*)(unsigned long long)g,
        (lvoid*)(unsigned int)(unsigned long long)l,   // low 32b = LDS offset
        16, 0, 0);
}

__device__ __forceinline__ short f2h(float f) {
    union { _Float16 h; short s; } u;
    u.h = (_Float16)f;                 // single v_cvt_f16_f32 (RNE)
    return u.s;
}

// XOR-swizzled element offset inside a [rows][64]-f16 tile (16B blocks).
__device__ __forceinline__ int sw8(int r, int k8) {       // k8 = octet 0..7
    return (r << 6) + ((k8 ^ (r & 7)) << 3);
}
__device__ __forceinline__ int swe(int r, int k) {        // element-level
    return (r << 6) + (((k >> 3) ^ (r & 7)) << 3) + (k & 7);
}

// workspace layout (SHORT offsets). Every plane = 4194304 shorts (8 MB).
#define PLANE   4194304UL
#define OFF_WH  (0UL * PLANE)    // [4][1024][1024] W f16; Wq pre-scaled log2e/8
#define OFF_XH  (1UL * PLANE)    // [4096][1024] x f16
#define OFF_QH  (2UL * PLANE)    // [B,H,N,DK] f16
#define OFF_KH  (4UL * PLANE)    // f16
#define OFF_VTH (5UL * PLANE)    // [B,H,DK,N] f16
#define OFF_CH  (6UL * PLANE)    // [B,N,M] concat f16

#define QSCALE  (0.125f * 1.44269504f)   // 1/8 attn scale * log2(e)

// ---------------------------------------------------------------------------
// Pre-split: W -> f16 (Wq scaled by log2e/8); x -> f16.
// ---------------------------------------------------------------------------
__global__ __launch_bounds__(256) void split_wx(
    const float* __restrict__ Wq, const float* __restrict__ Wk,
    const float* __restrict__ Wv, const float* __restrict__ Wo,
    const float* __restrict__ x,
    unsigned short* __restrict__ wh, unsigned short* __restrict__ xh)
{
    const int i = blockIdx.x * 256 + threadIdx.x;   // float4 idx, 2097152 total
    if (i < 1048576) {                               // weights
        const float* src = (i < 262144) ? Wq : (i < 524288) ? Wk
                         : (i < 786432) ? Wv : Wo;
        const float sc = (i < 262144) ? QSCALE : 1.0f;   // fold scale+log2e
        const int local = i & 262143;
        float4 v = ((const float4*)src)[local];
        short4 h;
        h.x = f2h(v.x * sc); h.y = f2h(v.y * sc);
        h.z = f2h(v.z * sc); h.w = f2h(v.w * sc);
        ((short4*)(wh + (size_t)(i >> 18) * 1048576))[local] = h;
    } else {                                         // x
        const int local = i - 1048576;
        float4 v = ((const float4*)x)[local];
        short4 h;
        h.x = f2h(v.x); h.y = f2h(v.y); h.z = f2h(v.z); h.w = f2h(v.w);
        ((short4*)xh)[local] = h;
    }
}

// ---------------------------------------------------------------------------
// Unified 1-term QKV GEMM (f16), R23 config restored: 256 threads / 4 waves
// (2x2 of 64x64), 128x128 tile. ONE launch (8,32,3) = 768 blocks = 3/CU,
// LDS 32KB, 32 MFMA per barrier per wave.
// z=0: Q; z=1: K; z=2: V^T (packed short4 stores).
// ---------------------------------------------------------------------------
__global__ __launch_bounds__(256, 4) void gemm_qkv(
    unsigned short* __restrict__ wsS,
    const float* __restrict__ bq, const float* __restrict__ bk,
    const float* __restrict__ bv)
{
    __shared__ unsigned short Ash[128 * 64];
    __shared__ unsigned short Bsh[128 * 64];

    const int mode = blockIdx.z;                     // 0 Q, 1 K, 2 V
    const unsigned short* Ah = wsS + OFF_XH;
    const unsigned short* Wh = wsS + OFF_WH + (size_t)mode * 1048576;

    const int tid  = threadIdx.x;
    const int lane = tid & 63;
    const int lm   = lane & 15;
    const int quad = lane >> 4;
    const int w    = tid >> 6;
    const int wr   = w >> 1, wc = w & 1;

    const int row0 = blockIdx.y * 128;
    const int col0 = blockIdx.x * 128;

    const int srow = lane >> 3;
    const int soct = (lane & 7) ^ (srow & 7);

    f32x4 acc[4][4] = {};

    for (int k0 = 0; k0 < 1024; k0 += 64) {
        if (k0) __syncthreads();
        #pragma unroll
        for (int i = 0; i < 4; ++i) {
            const int rb = w * 32 + i * 8;           // wave-uniform row base
            gll16(&Ah[(size_t)(row0 + rb + srow) * 1024 + k0 + soct * 8],
                  &Ash[rb * 64]);
            gll16(&Wh[(size_t)(col0 + rb + srow) * 1024 + k0 + soct * 8],
                  &Bsh[rb * 64]);
        }
        __syncthreads();
        #pragma unroll
        for (int ks = 0; ks < 2; ++ks) {
            f16x8 afh[4], bfh[4];
            #pragma unroll
            for (int mi = 0; mi < 4; ++mi)
                afh[mi] = *(const f16x8*)&Ash[sw8(wr * 64 + mi * 16 + lm, ks * 4 + quad)];
            #pragma unroll
            for (int ni = 0; ni < 4; ++ni)
                bfh[ni] = *(const f16x8*)&Bsh[sw8(wc * 64 + ni * 16 + lm, ks * 4 + quad)];
            #pragma unroll
            for (int mi = 0; mi < 4; ++mi) {
                #pragma unroll
                for (int ni = 0; ni < 4; ++ni)
                    acc[mi][ni] = __builtin_amdgcn_mfma_f32_16x16x32_f16(
                        afh[mi], bfh[ni], acc[mi][ni], 0, 0, 0);
            }
        }
    }

    unsigned short* qh  = wsS + OFF_QH;
    unsigned short* kh  = wsS + OFF_KH;
    unsigned short* vth = wsS + OFF_VTH;

    if (mode == 2) {
        // V^T: 4 j-values are 4 CONSECUTIVE n -> one aligned 8B store each
        #pragma unroll
        for (int ni = 0; ni < 4; ++ni) {
            const int f = col0 + wc * 64 + ni * 16 + lm;
            const float bvv = bv[f];
            const int h = f >> 6, d = f & 63;
            #pragma unroll
            for (int mi = 0; mi < 4; ++mi) {
                const int rowb = row0 + wr * 64 + mi * 16 + quad * 4;
                const int bb = rowb >> 11, n = rowb & 2047;
                short4 pk;
                pk.x = f2h(acc[mi][ni][0] + bvv);
                pk.y = f2h(acc[mi][ni][1] + bvv);
                pk.z = f2h(acc[mi][ni][2] + bvv);
                pk.w = f2h(acc[mi][ni][3] + bvv);
                *(short4*)&vth[((size_t)(bb * 16 + h) * 64 + d) * 2048 + n] = pk;
            }
        }
        return;
    }

    const float* bias = (mode == 0) ? bq : bk;
    const float bscale = (mode == 0) ? QSCALE : 1.0f;
    unsigned short* dst = (mode == 0) ? qh : kh;

    #pragma unroll
    for (int ni = 0; ni < 4; ++ni) {
        const int f = col0 + wc * 64 + ni * 16 + lm;
        const float bvv = bias[f] * bscale;
        const int h = f >> 6, d = f & 63;
        #pragma unroll
        for (int mi = 0; mi < 4; ++mi) {
            #pragma unroll
            for (int j = 0; j < 4; ++j) {
                const int row = row0 + wr * 64 + mi * 16 + quad * 4 + j;
                const int bb = row >> 11, n = row & 2047;
                dst[((size_t)(bb * 16 + h) * 2048 + n) * 64 + d] =
                    f2h(acc[mi][ni][j] + bvv);
            }
        }
    }
}

// ---------------------------------------------------------------------------
// 1-term output projection (f16), R23 config (unchanged): 128x64 tile,
// 256 threads / 4 waves, grid (16,32) = 512 blocks = 2 blocks/CU.
// LDS 24KB: A 128x64 + B 64x64. Per wave 64x32 output (acc[4][2]).
// ---------------------------------------------------------------------------
__global__ __launch_bounds__(256, 4) void gemm_out(
    const unsigned short* __restrict__ Ah,
    unsigned short* __restrict__ wsS,
    const float* __restrict__ bias_p, float* __restrict__ oout)
{
    __shared__ unsigned short Ash[128 * 64];
    __shared__ unsigned short Bsh[64 * 64];

    const unsigned short* Wh = wsS + OFF_WH + 3UL * 1048576;

    const int tid  = threadIdx.x;
    const int lane = tid & 63;
    const int lm   = lane & 15;
    const int quad = lane >> 4;
    const int w    = tid >> 6;          // 0..3
    const int wr   = w >> 1;            // 0..1  (64-row half)
    const int wc   = w & 1;             // 0..1  (32-col half)

    const int row0 = blockIdx.y * 128;
    const int col0 = blockIdx.x * 64;

    const int srow = lane >> 3;
    const int soct = (lane & 7) ^ (srow & 7);

    f32x4 acc[4][2] = {};

    for (int k0 = 0; k0 < 1024; k0 += 64) {
        if (k0) __syncthreads();
        #pragma unroll
        for (int i = 0; i < 4; ++i) {           // A: 128 rows, 4 gll16/wave
            const int rb = w * 32 + i * 8;
            gll16(&Ah[(size_t)(row0 + rb + srow) * 1024 + k0 + soct * 8],
                  &Ash[rb * 64]);
        }
        #pragma unroll
        for (int i = 0; i < 2; ++i) {           // B: 64 rows, 2 gll16/wave
            const int rb = w * 16 + i * 8;
            gll16(&Wh[(size_t)(col0 + rb + srow) * 1024 + k0 + soct * 8],
                  &Bsh[rb * 64]);
        }
        __syncthreads();
        #pragma unroll
        for (int ks = 0; ks < 2; ++ks) {
            f16x8 afh[4], bfh[2];
            #pragma unroll
            for (int mi = 0; mi < 4; ++mi)
                afh[mi] = *(const f16x8*)&Ash[sw8(wr * 64 + mi * 16 + lm, ks * 4 + quad)];
            #pragma unroll
            for (int ni = 0; ni < 2; ++ni)
                bfh[ni] = *(const f16x8*)&Bsh[sw8(wc * 32 + ni * 16 + lm, ks * 4 + quad)];
            #pragma unroll
            for (int mi = 0; mi < 4; ++mi) {
                #pragma unroll
                for (int ni = 0; ni < 2; ++ni)
                    acc[mi][ni] = __builtin_amdgcn_mfma_f32_16x16x32_f16(
                        afh[mi], bfh[ni], acc[mi][ni], 0, 0, 0);
            }
        }
    }

    #pragma unroll
    for (int ni = 0; ni < 2; ++ni) {
        const int f = col0 + wc * 32 + ni * 16 + lm;
        const float bvv = bias_p[f];
        #pragma unroll
        for (int mi = 0; mi < 4; ++mi) {
            #pragma unroll
            for (int j = 0; j < 4; ++j) {
                const int row = row0 + wr * 64 + mi * 16 + quad * 4 + j;
                oout[(size_t)row * 1024 + f] = acc[mi][ni][j] + bvv;
            }
        }
    }
}

// ---------------------------------------------------------------------------
// Flash attention (R25): QBLK=64 — 256 threads / 4 waves / 64 q-rows per
// block, 1024 blocks = 4 blocks/CU (LDS 40KB). Cross-tile pipeline
// unchanged from R22: iteration t does exp/P-write for tile t (s carried
// in regs), QK for t+1, PV for t. K/V dbuf, Psh single-buffer, setprio.
// ---------------------------------------------------------------------------
__global__ __launch_bounds__(256, 4) void attn_fast(
    const unsigned short* __restrict__ wsS, const float* __restrict__ mask,
    unsigned short* __restrict__ ch)
{
    __shared__ unsigned short Ksh[2][64 * 64];   // [buf][kcol][d]
    __shared__ unsigned short Vth[2][64 * 64];   // [buf][d][k]
    __shared__ unsigned short Psh[4][16 * 64];   // per-wave [q][k]

    const int tid  = threadIdx.x;
    const int lane = tid & 63;
    const int lm   = lane & 15;
    const int quad = lane >> 4;
    const int w    = tid >> 6;                   // 0..3

    const int q0 = blockIdx.x * 64;
    const int h  = blockIdx.y;
    const int b  = blockIdx.z;
    const int bh = b * 16 + h;

    const unsigned short* Qhg = wsS + OFF_QH  + (size_t)bh * 2048 * 64;
    const unsigned short* Khg = wsS + OFF_KH  + (size_t)bh * 2048 * 64;
    const unsigned short* Vhg = wsS + OFF_VTH + (size_t)bh * 64 * 2048;

    // Q frags in registers (this wave's 16 q-rows); scale+log2e pre-folded
    f16x8 qfh[2];
    #pragma unroll
    for (int ks = 0; ks < 2; ++ks) {
        const size_t qo = (size_t)(q0 + w * 16 + lm) * 64 + ks * 32 + quad * 8;
        qfh[ks] = *(const f16x8*)&Qhg[qo];
    }

    const int srow = lane >> 3;
    const int soct = (lane & 7) ^ (srow & 7);
    const int rb   = w * 16;                     // 16 staging rows per wave

    const int qwbase = q0 + w * 16 + quad * 4;
    // strength-reduced mask row pointers (advance 64 floats per tile)
    const float* mp0 = mask + (size_t)b * 2048 * 2048
                     + (size_t)(qwbase + 0) * 2048 + lm;
    const float* mp1 = mp0 + 2048;
    const float* mp2 = mp0 + 4096;
    const float* mp3 = mp0 + 6144;

    // prologue: stage K(0),V(0),K(1); preload mask(0); barrier; QK(0)
    #pragma unroll
    for (int i = 0; i < 2; ++i) {
        gll16(&Khg[(size_t)(rb + i * 8 + srow) * 64 + soct * 8],
              &Ksh[0][(rb + i * 8) * 64]);
        gll16(&Vhg[(size_t)(rb + i * 8 + srow) * 2048 + soct * 8],
              &Vth[0][(rb + i * 8) * 64]);
    }
    #pragma unroll
    for (int i = 0; i < 2; ++i)
        gll16(&Khg[(size_t)(64 + rb + i * 8 + srow) * 64 + soct * 8],
              &Ksh[1][(rb + i * 8) * 64]);

    float mc0[4], mc1[4], mc2[4], mc3[4];
    #pragma unroll
    for (int ni = 0; ni < 4; ++ni) {
        mc0[ni] = mp0[ni * 16];
        mc1[ni] = mp1[ni * 16];
        mc2[ni] = mp2[ni * 16];
        mc3[ni] = mp3[ni * 16];
    }
    mp0 += 64; mp1 += 64; mp2 += 64; mp3 += 64;

    __syncthreads();   // K(0), V(0) resident

    f32x4 scur[4] = {};
    __builtin_amdgcn_s_setprio(1);
    #pragma unroll
    for (int ks = 0; ks < 2; ++ks) {
        #pragma unroll
        for (int ni = 0; ni < 4; ++ni) {
            f16x8 kh = *(const f16x8*)&Ksh[0][sw8(ni * 16 + lm, ks * 4 + quad)];
            scur[ni] = __builtin_amdgcn_mfma_f32_16x16x32_f16(qfh[ks], kh, scur[ni], 0, 0, 0);
        }
    }
    __builtin_amdgcn_s_setprio(0);

    f32x4 o[4] = {};
    float lsum[4] = {0.f, 0.f, 0.f, 0.f};

    for (int t = 0; t < 32; ++t) {
        const int p = t & 1;

        __syncthreads();   // K(t+1) in Ksh[1-p], V(t) in Vth[p] resident

        // mask(t+1) preload + V(t+1) stage (into Vth[1-p]; its last reads
        // were PV(t-1), pre-barrier)
        float mn0[4], mn1[4], mn2[4], mn3[4];
        if (t < 31) {
            #pragma unroll
            for (int ni = 0; ni < 4; ++ni) {
                mn0[ni] = mp0[ni * 16];
                mn1[ni] = mp1[ni * 16];
                mn2[ni] = mp2[ni * 16];
                mn3[ni] = mp3[ni * 16];
            }
            mp0 += 64; mp1 += 64; mp2 += 64; mp3 += 64;
            #pragma unroll
            for (int i = 0; i < 2; ++i)
                gll16(&Vhg[(size_t)(rb + i * 8 + srow) * 2048 + (t + 1) * 64 + soct * 8],
                      &Vth[1 - p][(rb + i * 8) * 64]);
        }

        // exp2(tile t): s and mask both a full tile old — zero stall
        #pragma unroll
        for (int ni = 0; ni < 4; ++ni) {
            const float pv0 = __builtin_amdgcn_exp2f(scur[ni][0] * mc0[ni]);
            const float pv1 = __builtin_amdgcn_exp2f(scur[ni][1] * mc1[ni]);
            const float pv2 = __builtin_amdgcn_exp2f(scur[ni][2] * mc2[ni]);
            const float pv3 = __builtin_amdgcn_exp2f(scur[ni][3] * mc3[ni]);
            lsum[0] += pv0; lsum[1] += pv1; lsum[2] += pv2; lsum[3] += pv3;
            Psh[w][swe(quad * 4 + 0, ni * 16 + lm)] = f2h(pv0);
            Psh[w][swe(quad * 4 + 1, ni * 16 + lm)] = f2h(pv1);
            Psh[w][swe(quad * 4 + 2, ni * 16 + lm)] = f2h(pv2);
            Psh[w][swe(quad * 4 + 3, ni * 16 + lm)] = f2h(pv3);
        }

        // stage K(t+2) into Ksh[p] (last read by QK(t), pre-barrier)
        if (t < 30) {
            #pragma unroll
            for (int i = 0; i < 2; ++i)
                gll16(&Khg[(size_t)((t + 2) * 64 + rb + i * 8 + srow) * 64 + soct * 8],
                      &Ksh[p][(rb + i * 8) * 64]);
        }

        // QK(t+1) from Ksh[1-p] — fills the P write->read gap with MFMAs
        f32x4 snew[4] = {};
        if (t < 31) {
            __builtin_amdgcn_s_setprio(1);
            #pragma unroll
            for (int ks = 0; ks < 2; ++ks) {
                #pragma unroll
                for (int ni = 0; ni < 4; ++ni) {
                    f16x8 kh = *(const f16x8*)&Ksh[1 - p][sw8(ni * 16 + lm, ks * 4 + quad)];
                    snew[ni] = __builtin_amdgcn_mfma_f32_16x16x32_f16(qfh[ks], kh, snew[ni], 0, 0, 0);
                }
            }
            __builtin_amdgcn_s_setprio(0);
        }

        // PV(t): P round-trip latency covered by QK(t+1) above
        __builtin_amdgcn_s_setprio(1);
        #pragma unroll
        for (int ks = 0; ks < 2; ++ks) {
            f16x8 ph = *(const f16x8*)&Psh[w][sw8(lm, ks * 4 + quad)];
            #pragma unroll
            for (int ni = 0; ni < 4; ++ni) {
                f16x8 vh = *(const f16x8*)&Vth[p][sw8(ni * 16 + lm, ks * 4 + quad)];
                o[ni] = __builtin_amdgcn_mfma_f32_16x16x32_f16(ph, vh, o[ni], 0, 0, 0);
            }
        }
        __builtin_amdgcn_s_setprio(0);

        // rotate carried registers
        if (t < 31) {
            #pragma unroll
            for (int ni = 0; ni < 4; ++ni) {
                scur[ni] = snew[ni];
                mc0[ni] = mn0[ni]; mc1[ni] = mn1[ni];
                mc2[ni] = mn2[ni]; mc3[ni] = mn3[ni];
            }
        }
    }

    // epilogue: one cross-lane row-sum reduction, normalize, store concat f16
    #pragma unroll
    for (int j = 0; j < 4; ++j) {
        float ls = lsum[j];
        ls += __shfl_xor(ls, 1);
        ls += __shfl_xor(ls, 2);
        ls += __shfl_xor(ls, 4);
        ls += __shfl_xor(ls, 8);
        const float inv = 1.0f / ls;
        const int q = qwbase + j;
        #pragma unroll
        for (int ni = 0; ni < 4; ++ni)
            ch[((size_t)b * 2048 + q) * 1024 + h * 64 + ni * 16 + lm] =
                (unsigned short)f2h(o[ni][j] * inv);
    }
}

extern "C" void kernel_launch(void* const* d_in, const int* in_sizes, int n_in,
                              void* d_out, int out_size, void* d_ws, size_t ws_size,
                              hipStream_t stream) {
    const float* x    = (const float*)d_in[0];
    const float* mask = (const float*)d_in[1];
    const float* Wq   = (const float*)d_in[2];
    const float* bq   = (const float*)d_in[3];
    const float* Wk   = (const float*)d_in[4];
    const float* bk   = (const float*)d_in[5];
    const float* Wv   = (const float*)d_in[6];
    const float* bv   = (const float*)d_in[7];
    const float* Wo   = (const float*)d_in[8];
    const float* bo   = (const float*)d_in[9];

    unsigned short* wsS = (unsigned short*)d_ws;

    // 1. pre-split: W -> f16 (Wq*log2e/8); x -> f16
    split_wx<<<8192, 256, 0, stream>>>(Wq, Wk, Wv, Wo, x,
        wsS + OFF_WH, wsS + OFF_XH);

    // 2. Q/K/V projections: 256 threads, 768 blocks = 3/CU (R23 proven)
    gemm_qkv<<<dim3(8, 32, 3), 256, 0, stream>>>(wsS, bq, bk, bv);

    // 3. flash attention: 256 threads, 64 q-rows/block, 1024 blocks = 4/CU
    attn_fast<<<dim3(32, 16, 2), 256, 0, stream>>>(wsS, mask, wsS + OFF_CH);

    // 4. output projection: 128x64 tiles, 512 blocks = 2/CU
    gemm_out<<<dim3(16, 32), 256, 0, stream>>>(
        wsS + OFF_CH, wsS, bo, (float*)d_out);
}

// Round 12
// 222.625 us; speedup vs baseline: 1.0298x; 1.0298x over previous
//
#include <hip/hip_runtime.h>
#include <hip/hip_bf16.h>
#include <math.h>

// B=2, N=2048, M=1024, H=16, DK=64. fp32 in/out.
// R26 = R23 restored (best known: 223.9us — attn 512thr/128q, qkv 256thr,
// out 128x64; R25's QBLK=64 doubled per-wave staging and cost 5us: the
// tile-sharing economy favors 8-wave blocks) + ONE safe attn trim:
// lsum via ones-MFMA. Row-sum of P == P @ ones: 2 extra MFMA/tile with an
// all-ones B-fragment (layout-independent: B=1 => D[m][n]=sum_k A[m][k]
// for ANY lane mapping) replace 16 VALU adds/tile AND the 4-stage shfl
// epilogue (D's columns are identical, so every lane holds its row sum).
// lsum now sums the f16-rounded P that PV consumes — self-consistent
// normalization; absmax expected ~1e-3 (thr 3.96e-3).
// Precision plan: all planes f16, 1-term everywhere; 1/8 scale AND log2e
// folded into Wq/bq; exp = raw v_exp_f32 (exp2).

typedef __attribute__((ext_vector_type(8))) _Float16 f16x8;
typedef __attribute__((ext_vector_type(4))) float f32x4;

typedef __attribute__((address_space(1))) void gvoid;   // global
typedef __attribute__((address_space(3))) void lvoid;   // LDS

// async 16B/lane global->LDS copy: 64 lanes -> 1KB at wave-uniform lds base
__device__ __forceinline__ void gll16(const void* g, void* l) {
    __builtin_amdgcn_global_load_lds(
        (gvoid*)(unsigned long long)g,
        (lvoid*)(unsigned int)(unsigned long long)l,   // low 32b = LDS offset
        16, 0, 0);
}

__device__ __forceinline__ short f2h(float f) {
    union { _Float16 h; short s; } u;
    u.h = (_Float16)f;                 // single v_cvt_f16_f32 (RNE)
    return u.s;
}

// XOR-swizzled element offset inside a [rows][64]-f16 tile (16B blocks).
__device__ __forceinline__ int sw8(int r, int k8) {       // k8 = octet 0..7
    return (r << 6) + ((k8 ^ (r & 7)) << 3);
}
__device__ __forceinline__ int swe(int r, int k) {        // element-level
    return (r << 6) + (((k >> 3) ^ (r & 7)) << 3) + (k & 7);
}

// workspace layout (SHORT offsets). Every plane = 4194304 shorts (8 MB).
#define PLANE   4194304UL
#define OFF_WH  (0UL * PLANE)    // [4][1024][1024] W f16; Wq pre-scaled log2e/8
#define OFF_XH  (1UL * PLANE)    // [4096][1024] x f16
#define OFF_QH  (2UL * PLANE)    // [B,H,N,DK] f16
#define OFF_KH  (4UL * PLANE)    // f16
#define OFF_VTH (5UL * PLANE)    // [B,H,DK,N] f16
#define OFF_CH  (6UL * PLANE)    // [B,N,M] concat f16

#define QSCALE  (0.125f * 1.44269504f)   // 1/8 attn scale * log2(e)

// ---------------------------------------------------------------------------
// Pre-split: W -> f16 (Wq scaled by log2e/8); x -> f16.
// ---------------------------------------------------------------------------
__global__ __launch_bounds__(256) void split_wx(
    const float* __restrict__ Wq, const float* __restrict__ Wk,
    const float* __restrict__ Wv, const float* __restrict__ Wo,
    const float* __restrict__ x,
    unsigned short* __restrict__ wh, unsigned short* __restrict__ xh)
{
    const int i = blockIdx.x * 256 + threadIdx.x;   // float4 idx, 2097152 total
    if (i < 1048576) {                               // weights
        const float* src = (i < 262144) ? Wq : (i < 524288) ? Wk
                         : (i < 786432) ? Wv : Wo;
        const float sc = (i < 262144) ? QSCALE : 1.0f;   // fold scale+log2e
        const int local = i & 262143;
        float4 v = ((const float4*)src)[local];
        short4 h;
        h.x = f2h(v.x * sc); h.y = f2h(v.y * sc);
        h.z = f2h(v.z * sc); h.w = f2h(v.w * sc);
        ((short4*)(wh + (size_t)(i >> 18) * 1048576))[local] = h;
    } else {                                         // x
        const int local = i - 1048576;
        float4 v = ((const float4*)x)[local];
        short4 h;
        h.x = f2h(v.x); h.y = f2h(v.y); h.z = f2h(v.z); h.w = f2h(v.w);
        ((short4*)xh)[local] = h;
    }
}

// ---------------------------------------------------------------------------
// Unified 1-term QKV GEMM (f16), R23 config: 256 threads / 4 waves
// (2x2 of 64x64), 128x128 tile. ONE launch (8,32,3) = 768 blocks = 3/CU,
// LDS 32KB, 32 MFMA per barrier per wave.
// z=0: Q; z=1: K; z=2: V^T (packed short4 stores).
// ---------------------------------------------------------------------------
__global__ __launch_bounds__(256, 4) void gemm_qkv(
    unsigned short* __restrict__ wsS,
    const float* __restrict__ bq, const float* __restrict__ bk,
    const float* __restrict__ bv)
{
    __shared__ unsigned short Ash[128 * 64];
    __shared__ unsigned short Bsh[128 * 64];

    const int mode = blockIdx.z;                     // 0 Q, 1 K, 2 V
    const unsigned short* Ah = wsS + OFF_XH;
    const unsigned short* Wh = wsS + OFF_WH + (size_t)mode * 1048576;

    const int tid  = threadIdx.x;
    const int lane = tid & 63;
    const int lm   = lane & 15;
    const int quad = lane >> 4;
    const int w    = tid >> 6;
    const int wr   = w >> 1, wc = w & 1;

    const int row0 = blockIdx.y * 128;
    const int col0 = blockIdx.x * 128;

    const int srow = lane >> 3;
    const int soct = (lane & 7) ^ (srow & 7);

    f32x4 acc[4][4] = {};

    for (int k0 = 0; k0 < 1024; k0 += 64) {
        if (k0) __syncthreads();
        #pragma unroll
        for (int i = 0; i < 4; ++i) {
            const int rb = w * 32 + i * 8;           // wave-uniform row base
            gll16(&Ah[(size_t)(row0 + rb + srow) * 1024 + k0 + soct * 8],
                  &Ash[rb * 64]);
            gll16(&Wh[(size_t)(col0 + rb + srow) * 1024 + k0 + soct * 8],
                  &Bsh[rb * 64]);
        }
        __syncthreads();
        #pragma unroll
        for (int ks = 0; ks < 2; ++ks) {
            f16x8 afh[4], bfh[4];
            #pragma unroll
            for (int mi = 0; mi < 4; ++mi)
                afh[mi] = *(const f16x8*)&Ash[sw8(wr * 64 + mi * 16 + lm, ks * 4 + quad)];
            #pragma unroll
            for (int ni = 0; ni < 4; ++ni)
                bfh[ni] = *(const f16x8*)&Bsh[sw8(wc * 64 + ni * 16 + lm, ks * 4 + quad)];
            #pragma unroll
            for (int mi = 0; mi < 4; ++mi) {
                #pragma unroll
                for (int ni = 0; ni < 4; ++ni)
                    acc[mi][ni] = __builtin_amdgcn_mfma_f32_16x16x32_f16(
                        afh[mi], bfh[ni], acc[mi][ni], 0, 0, 0);
            }
        }
    }

    unsigned short* qh  = wsS + OFF_QH;
    unsigned short* kh  = wsS + OFF_KH;
    unsigned short* vth = wsS + OFF_VTH;

    if (mode == 2) {
        // V^T: 4 j-values are 4 CONSECUTIVE n -> one aligned 8B store each
        #pragma unroll
        for (int ni = 0; ni < 4; ++ni) {
            const int f = col0 + wc * 64 + ni * 16 + lm;
            const float bvv = bv[f];
            const int h = f >> 6, d = f & 63;
            #pragma unroll
            for (int mi = 0; mi < 4; ++mi) {
                const int rowb = row0 + wr * 64 + mi * 16 + quad * 4;
                const int bb = rowb >> 11, n = rowb & 2047;
                short4 pk;
                pk.x = f2h(acc[mi][ni][0] + bvv);
                pk.y = f2h(acc[mi][ni][1] + bvv);
                pk.z = f2h(acc[mi][ni][2] + bvv);
                pk.w = f2h(acc[mi][ni][3] + bvv);
                *(short4*)&vth[((size_t)(bb * 16 + h) * 64 + d) * 2048 + n] = pk;
            }
        }
        return;
    }

    const float* bias = (mode == 0) ? bq : bk;
    const float bscale = (mode == 0) ? QSCALE : 1.0f;
    unsigned short* dst = (mode == 0) ? qh : kh;

    #pragma unroll
    for (int ni = 0; ni < 4; ++ni) {
        const int f = col0 + wc * 64 + ni * 16 + lm;
        const float bvv = bias[f] * bscale;
        const int h = f >> 6, d = f & 63;
        #pragma unroll
        for (int mi = 0; mi < 4; ++mi) {
            #pragma unroll
            for (int j = 0; j < 4; ++j) {
                const int row = row0 + wr * 64 + mi * 16 + quad * 4 + j;
                const int bb = row >> 11, n = row & 2047;
                dst[((size_t)(bb * 16 + h) * 2048 + n) * 64 + d] =
                    f2h(acc[mi][ni][j] + bvv);
            }
        }
    }
}

// ---------------------------------------------------------------------------
// 1-term output projection (f16), R23 config: 128x64 tile, 256 threads /
// 4 waves, grid (16,32) = 512 blocks = 2 blocks/CU. LDS 24KB.
// ---------------------------------------------------------------------------
__global__ __launch_bounds__(256, 4) void gemm_out(
    const unsigned short* __restrict__ Ah,
    unsigned short* __restrict__ wsS,
    const float* __restrict__ bias_p, float* __restrict__ oout)
{
    __shared__ unsigned short Ash[128 * 64];
    __shared__ unsigned short Bsh[64 * 64];

    const unsigned short* Wh = wsS + OFF_WH + 3UL * 1048576;

    const int tid  = threadIdx.x;
    const int lane = tid & 63;
    const int lm   = lane & 15;
    const int quad = lane >> 4;
    const int w    = tid >> 6;          // 0..3
    const int wr   = w >> 1;            // 0..1  (64-row half)
    const int wc   = w & 1;             // 0..1  (32-col half)

    const int row0 = blockIdx.y * 128;
    const int col0 = blockIdx.x * 64;

    const int srow = lane >> 3;
    const int soct = (lane & 7) ^ (srow & 7);

    f32x4 acc[4][2] = {};

    for (int k0 = 0; k0 < 1024; k0 += 64) {
        if (k0) __syncthreads();
        #pragma unroll
        for (int i = 0; i < 4; ++i) {           // A: 128 rows, 4 gll16/wave
            const int rb = w * 32 + i * 8;
            gll16(&Ah[(size_t)(row0 + rb + srow) * 1024 + k0 + soct * 8],
                  &Ash[rb * 64]);
        }
        #pragma unroll
        for (int i = 0; i < 2; ++i) {           // B: 64 rows, 2 gll16/wave
            const int rb = w * 16 + i * 8;
            gll16(&Wh[(size_t)(col0 + rb + srow) * 1024 + k0 + soct * 8],
                  &Bsh[rb * 64]);
        }
        __syncthreads();
        #pragma unroll
        for (int ks = 0; ks < 2; ++ks) {
            f16x8 afh[4], bfh[2];
            #pragma unroll
            for (int mi = 0; mi < 4; ++mi)
                afh[mi] = *(const f16x8*)&Ash[sw8(wr * 64 + mi * 16 + lm, ks * 4 + quad)];
            #pragma unroll
            for (int ni = 0; ni < 2; ++ni)
                bfh[ni] = *(const f16x8*)&Bsh[sw8(wc * 32 + ni * 16 + lm, ks * 4 + quad)];
            #pragma unroll
            for (int mi = 0; mi < 4; ++mi) {
                #pragma unroll
                for (int ni = 0; ni < 2; ++ni)
                    acc[mi][ni] = __builtin_amdgcn_mfma_f32_16x16x32_f16(
                        afh[mi], bfh[ni], acc[mi][ni], 0, 0, 0);
            }
        }
    }

    #pragma unroll
    for (int ni = 0; ni < 2; ++ni) {
        const int f = col0 + wc * 32 + ni * 16 + lm;
        const float bvv = bias_p[f];
        #pragma unroll
        for (int mi = 0; mi < 4; ++mi) {
            #pragma unroll
            for (int j = 0; j < 4; ++j) {
                const int row = row0 + wr * 64 + mi * 16 + quad * 4 + j;
                oout[(size_t)row * 1024 + f] = acc[mi][ni][j] + bvv;
            }
        }
    }
}

// ---------------------------------------------------------------------------
// Flash attention (R26): R23 structure (512 threads / 8 waves / 128 q-rows,
// grid 512 = 2 blocks/CU, LDS 48KB, cross-tile pipeline) + lsum via
// ones-MFMA (2 extra MFMA/tile replace 16 VALU adds + the shfl epilogue;
// every lane ends up holding its full row sum).
// ---------------------------------------------------------------------------
__global__ __launch_bounds__(512, 4) void attn_fast(
    const unsigned short* __restrict__ wsS, const float* __restrict__ mask,
    unsigned short* __restrict__ ch)
{
    __shared__ unsigned short Ksh[2][64 * 64];   // [buf][kcol][d]
    __shared__ unsigned short Vth[2][64 * 64];   // [buf][d][k]
    __shared__ unsigned short Psh[8][16 * 64];   // per-wave [q][k]

    const int tid  = threadIdx.x;
    const int lane = tid & 63;
    const int lm   = lane & 15;
    const int quad = lane >> 4;
    const int w    = tid >> 6;                   // 0..7

    const int q0 = blockIdx.x * 128;
    const int h  = blockIdx.y;
    const int b  = blockIdx.z;
    const int bh = b * 16 + h;

    const unsigned short* Qhg = wsS + OFF_QH  + (size_t)bh * 2048 * 64;
    const unsigned short* Khg = wsS + OFF_KH  + (size_t)bh * 2048 * 64;
    const unsigned short* Vhg = wsS + OFF_VTH + (size_t)bh * 64 * 2048;

    // Q frags in registers (this wave's 16 q-rows); scale+log2e pre-folded
    f16x8 qfh[2];
    #pragma unroll
    for (int ks = 0; ks < 2; ++ks) {
        const size_t qo = (size_t)(q0 + w * 16 + lm) * 64 + ks * 32 + quad * 8;
        qfh[ks] = *(const f16x8*)&Qhg[qo];
    }

    // all-ones B fragment: D = P @ ones gives row sums in every column
    const f16x8 ones = {(_Float16)1.f, (_Float16)1.f, (_Float16)1.f,
                        (_Float16)1.f, (_Float16)1.f, (_Float16)1.f,
                        (_Float16)1.f, (_Float16)1.f};

    const int srow = lane >> 3;
    const int soct = (lane & 7) ^ (srow & 7);
    const int rb   = w * 8;                      // 8 rows per wave (8 waves)

    const int qwbase = q0 + w * 16 + quad * 4;
    // strength-reduced mask row pointers (advance 64 floats per tile)
    const float* mp0 = mask + (size_t)b * 2048 * 2048
                     + (size_t)(qwbase + 0) * 2048 + lm;
    const float* mp1 = mp0 + 2048;
    const float* mp2 = mp0 + 4096;
    const float* mp3 = mp0 + 6144;

    // prologue: stage K(0),V(0),K(1); preload mask(0); barrier; QK(0)
    gll16(&Khg[(size_t)(rb + srow) * 64 + soct * 8],        &Ksh[0][rb * 64]);
    gll16(&Vhg[(size_t)(rb + srow) * 2048 + soct * 8],      &Vth[0][rb * 64]);
    gll16(&Khg[(size_t)(64 + rb + srow) * 64 + soct * 8],   &Ksh[1][rb * 64]);

    float mc0[4], mc1[4], mc2[4], mc3[4];
    #pragma unroll
    for (int ni = 0; ni < 4; ++ni) {
        mc0[ni] = mp0[ni * 16];
        mc1[ni] = mp1[ni * 16];
        mc2[ni] = mp2[ni * 16];
        mc3[ni] = mp3[ni * 16];
    }
    mp0 += 64; mp1 += 64; mp2 += 64; mp3 += 64;

    __syncthreads();   // K(0), V(0) resident

    f32x4 scur[4] = {};
    __builtin_amdgcn_s_setprio(1);
    #pragma unroll
    for (int ks = 0; ks < 2; ++ks) {
        #pragma unroll
        for (int ni = 0; ni < 4; ++ni) {
            f16x8 kh = *(const f16x8*)&Ksh[0][sw8(ni * 16 + lm, ks * 4 + quad)];
            scur[ni] = __builtin_amdgcn_mfma_f32_16x16x32_f16(qfh[ks], kh, scur[ni], 0, 0, 0);
        }
    }
    __builtin_amdgcn_s_setprio(0);

    f32x4 o[4] = {};
    f32x4 ls = {};                               // row sums via ones-MFMA

    for (int t = 0; t < 32; ++t) {
        const int p = t & 1;

        __syncthreads();   // K(t+1) in Ksh[1-p], V(t) in Vth[p] resident

        // mask(t+1) preload + V(t+1) stage (into Vth[1-p]; its last reads
        // were PV(t-1), pre-barrier)
        float mn0[4], mn1[4], mn2[4], mn3[4];
        if (t < 31) {
            #pragma unroll
            for (int ni = 0; ni < 4; ++ni) {
                mn0[ni] = mp0[ni * 16];
                mn1[ni] = mp1[ni * 16];
                mn2[ni] = mp2[ni * 16];
                mn3[ni] = mp3[ni * 16];
            }
            mp0 += 64; mp1 += 64; mp2 += 64; mp3 += 64;
            gll16(&Vhg[(size_t)(rb + srow) * 2048 + (t + 1) * 64 + soct * 8],
                  &Vth[1 - p][rb * 64]);
        }

        // exp2(tile t): s and mask both a full tile old — zero stall.
        // No VALU lsum: row sums come from the ones-MFMA below.
        #pragma unroll
        for (int ni = 0; ni < 4; ++ni) {
            const float pv0 = __builtin_amdgcn_exp2f(scur[ni][0] * mc0[ni]);
            const float pv1 = __builtin_amdgcn_exp2f(scur[ni][1] * mc1[ni]);
            const float pv2 = __builtin_amdgcn_exp2f(scur[ni][2] * mc2[ni]);
            const float pv3 = __builtin_amdgcn_exp2f(scur[ni][3] * mc3[ni]);
            Psh[w][swe(quad * 4 + 0, ni * 16 + lm)] = f2h(pv0);
            Psh[w][swe(quad * 4 + 1, ni * 16 + lm)] = f2h(pv1);
            Psh[w][swe(quad * 4 + 2, ni * 16 + lm)] = f2h(pv2);
            Psh[w][swe(quad * 4 + 3, ni * 16 + lm)] = f2h(pv3);
        }

        // stage K(t+2) into Ksh[p] (last read by QK(t), pre-barrier)
        if (t < 30)
            gll16(&Khg[(size_t)((t + 2) * 64 + rb + srow) * 64 + soct * 8],
                  &Ksh[p][rb * 64]);

        // QK(t+1) from Ksh[1-p] — fills the P write->read gap with MFMAs
        f32x4 snew[4] = {};
        if (t < 31) {
            __builtin_amdgcn_s_setprio(1);
            #pragma unroll
            for (int ks = 0; ks < 2; ++ks) {
                #pragma unroll
                for (int ni = 0; ni < 4; ++ni) {
                    f16x8 kh = *(const f16x8*)&Ksh[1 - p][sw8(ni * 16 + lm, ks * 4 + quad)];
                    snew[ni] = __builtin_amdgcn_mfma_f32_16x16x32_f16(qfh[ks], kh, snew[ni], 0, 0, 0);
                }
            }
            __builtin_amdgcn_s_setprio(0);
        }

        // PV(t) + row-sum MFMA: ls = P @ ones (accumulates across tiles)
        __builtin_amdgcn_s_setprio(1);
        #pragma unroll
        for (int ks = 0; ks < 2; ++ks) {
            f16x8 ph = *(const f16x8*)&Psh[w][sw8(lm, ks * 4 + quad)];
            ls = __builtin_amdgcn_mfma_f32_16x16x32_f16(ph, ones, ls, 0, 0, 0);
            #pragma unroll
            for (int ni = 0; ni < 4; ++ni) {
                f16x8 vh = *(const f16x8*)&Vth[p][sw8(ni * 16 + lm, ks * 4 + quad)];
                o[ni] = __builtin_amdgcn_mfma_f32_16x16x32_f16(ph, vh, o[ni], 0, 0, 0);
            }
        }
        __builtin_amdgcn_s_setprio(0);

        // rotate carried registers
        if (t < 31) {
            #pragma unroll
            for (int ni = 0; ni < 4; ++ni) {
                scur[ni] = snew[ni];
                mc0[ni] = mn0[ni]; mc1[ni] = mn1[ni];
                mc2[ni] = mn2[ni]; mc3[ni] = mn3[ni];
            }
        }
    }

    // epilogue: every lane already holds its full row sums in ls[j]
    #pragma unroll
    for (int j = 0; j < 4; ++j) {
        const float inv = 1.0f / ls[j];
        const int q = qwbase + j;
        #pragma unroll
        for (int ni = 0; ni < 4; ++ni)
            ch[((size_t)b * 2048 + q) * 1024 + h * 64 + ni * 16 + lm] =
                (unsigned short)f2h(o[ni][j] * inv);
    }
}

extern "C" void kernel_launch(void* const* d_in, const int* in_sizes, int n_in,
                              void* d_out, int out_size, void* d_ws, size_t ws_size,
                              hipStream_t stream) {
    const float* x    = (const float*)d_in[0];
    const float* mask = (const float*)d_in[1];
    const float* Wq   = (const float*)d_in[2];
    const float* bq   = (const float*)d_in[3];
    const float* Wk   = (const float*)d_in[4];
    const float* bk   = (const float*)d_in[5];
    const float* Wv   = (const float*)d_in[6];
    const float* bv   = (const float*)d_in[7];
    const float* Wo   = (const float*)d_in[8];
    const float* bo   = (const float*)d_in[9];

    unsigned short* wsS = (unsigned short*)d_ws;

    // 1. pre-split: W -> f16 (Wq*log2e/8); x -> f16
    split_wx<<<8192, 256, 0, stream>>>(Wq, Wk, Wv, Wo, x,
        wsS + OFF_WH, wsS + OFF_XH);

    // 2. Q/K/V projections: 256 threads, 768 blocks = 3/CU (R23 proven)
    gemm_qkv<<<dim3(8, 32, 3), 256, 0, stream>>>(wsS, bq, bk, bv);

    // 3. flash attention: 512 threads, 128 q-rows/block, cross-tile pipeline
    attn_fast<<<dim3(16, 16, 2), 512, 0, stream>>>(wsS, mask, wsS + OFF_CH);

    // 4. output projection: 128x64 tiles, 512 blocks = 2/CU
    gemm_out<<<dim3(16, 32), 256, 0, stream>>>(
        wsS + OFF_CH, wsS, bo, (float*)d_out);
}